// Round 13
// baseline (669.665 us; speedup 1.0000x reference)
//
#include <hip/hip_runtime.h>
#include <hip/hip_bf16.h>

typedef unsigned short u16;
typedef __bf16 bf16x8 __attribute__((ext_vector_type(8)));
typedef float f32x4 __attribute__((ext_vector_type(4)));

static __device__ __forceinline__ u16 f2b(float f) {
    __hip_bfloat16 h = __float2bfloat16(f);
    union { __hip_bfloat16 b; u16 u; } c;
    c.b = h;
    return c.u;
}

// fp32 -> bf16 bits, 8 elements per thread-iter
__global__ void cvt_f32_to_bf16(const float* __restrict__ in, u16* __restrict__ out, long n8) {
    long i = (long)blockIdx.x * blockDim.x + threadIdx.x;
    long stride = (long)gridDim.x * blockDim.x;
    for (long v = i; v < n8; v += stride) {
        const float4* p = reinterpret_cast<const float4*>(in) + 2 * v;
        float4 a = p[0];
        float4 b = p[1];
        uint4 o;
        o.x = (unsigned)f2b(a.x) | ((unsigned)f2b(a.y) << 16);
        o.y = (unsigned)f2b(a.z) | ((unsigned)f2b(a.w) << 16);
        o.z = (unsigned)f2b(b.x) | ((unsigned)f2b(b.y) << 16);
        o.w = (unsigned)f2b(b.z) | ((unsigned)f2b(b.w) << 16);
        reinterpret_cast<uint4*>(out)[v] = o;
    }
}

// W[K][N] fp32 -> Wt[N][K] bf16 bits, 32x32 LDS-tiled transpose
__global__ void transpose_cvt(const float* __restrict__ w, u16* __restrict__ wt, int K, int N) {
    __shared__ float tile[32][33];
    int bn = blockIdx.x * 32;
    int bk = blockIdx.y * 32;
    int tx = threadIdx.x & 31;
    int ty = threadIdx.x >> 5;
#pragma unroll
    for (int i = 0; i < 32; i += 8)
        tile[ty + i][tx] = w[(long)(bk + ty + i) * N + bn + tx];
    __syncthreads();
#pragma unroll
    for (int i = 0; i < 32; i += 8)
        wt[(long)(bn + ty + i) * K + bk + tx] = f2b(tile[tx][ty + i]);
}

static __device__ __forceinline__ void gl_lds16(const u16* g, u16* l) {
    __builtin_amdgcn_global_load_lds(
        (const __attribute__((address_space(1))) void*)g,
        (__attribute__((address_space(3))) void*)l, 16, 0, 0);
}

// ---------------------------------------------------------------------------
// R13 = R12 "flatmm" with the macro fixed: A-fragments DIRECT FROM GLOBAL
// (no A LDS), B via LDS (T2-swizzled, double-buffered), 256x256 tile.
// C = A[8192][4096] * Wt[4096][4096]^T
// 512 threads = 8 waves (2M x 4N), per-wave 128x64, BK=64, 64 K-tiles.
// Rationale: 8 schedule variants pinned at 237us; per-CU-K-tile LDS service
// (192 b128 ~ 2000 cyc) >> MFMA (620/SIMD) -> LDS-BW-bound. Dropping A from
// LDS cuts ds_reads 24->8 per wave per tile. A frag addressing: lane group
// {x,x+16,x+32,x+48} reads one contiguous 64B span of a row; the 4 wc-waves
// share the same 32KB A panel slice -> L1/L2-served re-reads.
// B schedule (2 barriers/tile): read all B frags up front; MFMA q0,q1;
// lgkm0+BAR (B(T) retired -> CB writable); stage B(T+2)->CB; MFMA q2,q3;
// vmcnt(4)+BAR (forces B(T+1), leaves B(T+2) in flight). A loads: plain
// vector loads, compiler-inserted waits, latency hidden under MFMA.
// LDS: 2 x B[256][64] = 64 KiB. T2 3-bit XOR swizzle on B (conflicts 0).
// ---------------------------------------------------------------------------
#define GK 4096L

#define PRIO1 __builtin_amdgcn_s_setprio(1);
#define PRIO0 __builtin_amdgcn_s_setprio(0);
#define BAR   __builtin_amdgcn_s_barrier();

#define STGB(dstbase, hh, ktel)                                                      \
    gl_lds16(Bsrc + (long)((hh) * 128) * GK + (ktel), (u16*)((dstbase) + (hh) * 16384)); \
    gl_lds16(Bsrc + (long)((hh) * 128 + 64) * GK + (ktel), (u16*)((dstbase) + (hh) * 16384 + 8192));

#define RD_B(buf)                                                                    \
    _Pragma("unroll") for (int ni = 0; ni < 4; ++ni)                                 \
        _Pragma("unroll") for (int kk = 0; kk < 2; ++kk)                             \
            bfr[ni][kk] = *(const bf16x8*)((buf) + bbase + ni * 2048 + (lcol ^ (kk * 64)));

// A fragment loads straight from global (bf16): row = lane&15 (+mi*16),
// k = kt + (lane>>4)*8 + kk*32. 16B per load.
#define RD_A(DST, MOFS, KT)                                                          \
    _Pragma("unroll") for (int mi = 0; mi < 4; ++mi)                                 \
        _Pragma("unroll") for (int kk = 0; kk < 2; ++kk)                             \
            DST[mi][kk] = *(const bf16x8*)(Afrag + ((MOFS) + mi * 16) * GK + (KT) + kk * 32);

// NB = B fragment base index into bfr[]; MO/NO = accumulator offsets.
#define MFMA_Q(AR, NB, MO, NO)                                                       \
    _Pragma("unroll") for (int mi = 0; mi < 4; ++mi)                                 \
        _Pragma("unroll") for (int ni = 0; ni < 2; ++ni)                             \
            _Pragma("unroll") for (int kk = 0; kk < 2; ++kk)                         \
                acc[(MO) + mi][(NO) + ni] = __builtin_amdgcn_mfma_f32_16x16x32_bf16( \
                    AR[mi][kk], bfr[(NB) + ni][kk], acc[(MO) + mi][(NO) + ni], 0, 0, 0);

__global__ __launch_bounds__(512, 2) void gemm_bf16_flat(
    const u16* __restrict__ A, const u16* __restrict__ Bt, float* __restrict__ C) {
    __shared__ __align__(16) u16 sh[2][256][64];   // B only: 2 bufs x 32 KiB
    char* shb = (char*)&sh[0][0][0];

    const int t = threadIdx.x;
    const int lane = t & 63;
    const int wid = t >> 6;
    const int wr = wid >> 2;   // 0..1
    const int wc = wid & 3;    // 0..3

    // T1: bijective XCD swizzle (512 wgs, 512 % 8 == 0)
    const int bid = blockIdx.x;
    const int wg = (bid & 7) * 64 + (bid >> 3);
    const int tm = wg >> 4;          // 0..31
    const int tn = wg & 15;          // 0..15

    // B staging source (pre-swizzled col, T2 involution)
    const int srow = t >> 3;
    const int scol = (((t & 7) ^ ((t >> 3) & 7)) * 8);
    const u16* Bsrc = Bt + (long)(tn * 256 + srow) * GK + scol;
    char* ldsBt = shb + t * 16;   // + buf*32768

    // B ds_read lane addressing (same involution)
    const int lrow = lane & 15;
    const int lcol = (((lane >> 4) ^ (lrow & 7)) << 4);
    const int bbase = (wc * 64 + lrow) * 128;

    // A fragment base: row = tm*256 + wr*128 + (lane&15), k base = (lane>>4)*8
    const u16* Afrag = A + (long)(tm * 256 + wr * 128 + lrow) * GK + ((lane >> 4) * 8);

    f32x4 acc[8][4] = {};
    bf16x8 a03[4][2], a47[4][2], bfr[4][2];

    // prologue: B(0)->buf0, B(1)->buf1 (8 gl_lds); vmcnt(4) -> B(0) resident
    STGB(ldsBt, 0, 0)
    STGB(ldsBt, 1, 0)
    STGB(ldsBt + 32768, 0, 64)
    STGB(ldsBt + 32768, 1, 64)
    asm volatile("s_waitcnt vmcnt(4)" ::: "memory");
    BAR

#pragma unroll 1
    for (int it = 0; it < 64; ++it) {
        const long kt = (long)it * 64;
        char* cb = shb + (it & 1) * 32768;
        // A frags (global) + B frags (LDS), all issued up front
        RD_A(a03, 0, kt)
        RD_B(cb)
        RD_A(a47, 64, kt)
        PRIO1
        MFMA_Q(a03, 0, 0, 0)
        MFMA_Q(a03, 2, 0, 2)
        PRIO0
        asm volatile("s_waitcnt lgkmcnt(0)" ::: "memory");
        BAR   // B(T) reads retired chip-wide -> CB writable
        if (it < 62) { STGB(ldsBt + (it & 1) * 32768, 0, kt + 128)
                       STGB(ldsBt + (it & 1) * 32768, 1, kt + 128) }
        PRIO1
        MFMA_Q(a47, 2, 4, 2)
        MFMA_Q(a47, 0, 4, 0)
        PRIO0
        if (it < 62) { asm volatile("s_waitcnt vmcnt(4)" ::: "memory"); }
        else         { asm volatile("s_waitcnt vmcnt(0)" ::: "memory"); }
        BAR   // B(T+1) resident
    }

    // epilogue: C/D layout col=lane&15, row=(lane>>4)*4+j
    const int crow = (lane >> 4) * 4;
    const int ccol = lane & 15;
    float* Cp = C + (long)(tm * 256 + wr * 128 + crow) * 4096 + tn * 256 + wc * 64 + ccol;
#pragma unroll
    for (int mi = 0; mi < 8; ++mi) {
#pragma unroll
        for (int j = 0; j < 4; ++j) {
            float* r = Cp + (long)(mi * 16 + j) * 4096;
#pragma unroll
            for (int ni = 0; ni < 4; ++ni)
                r[ni * 16] = acc[mi][ni][j];
        }
    }
}

// fallback (only if ws_size is too small): correct fp32 tiled GEMM
__global__ void gemm_f32_fallback(const float* __restrict__ A, const float* __restrict__ B,
                                  float* __restrict__ C, int M, int N, int K) {
    __shared__ float As[16][17];
    __shared__ float Bs[16][17];
    int tx = threadIdx.x & 15;
    int ty = threadIdx.x >> 4;
    int row = blockIdx.y * 16 + ty;
    int col = blockIdx.x * 16 + tx;
    float s = 0.f;
    for (int k0 = 0; k0 < K; k0 += 16) {
        As[ty][tx] = A[(long)row * K + k0 + tx];
        Bs[ty][tx] = B[(long)(k0 + ty) * N + col];
        __syncthreads();
#pragma unroll
        for (int kk = 0; kk < 16; ++kk) s += As[ty][kk] * Bs[kk][tx];
        __syncthreads();
    }
    C[(long)row * N + col] = s;
}

extern "C" void kernel_launch(void* const* d_in, const int* in_sizes, int n_in,
                              void* d_out, int out_size, void* d_ws, size_t ws_size,
                              hipStream_t stream) {
    const int M = 8192, K = 4096, N = 4096;
    const float* x = (const float*)d_in[0];       // [M][K] fp32
    const float* wte = (const float*)d_in[1];     // [K][N] fp32
    float* out = (float*)d_out;                   // [M][N] fp32

    const size_t need = (size_t)M * K * 2 + (size_t)K * N * 2;  // 96 MiB
    if (ws_size >= need) {
        u16* xb = (u16*)d_ws;                  // [M][K] bf16
        u16* wt = xb + (size_t)M * K;          // [N][K] bf16 (transposed)

        cvt_f32_to_bf16<<<2048, 256, 0, stream>>>(x, xb, (long)M * K / 8);

        dim3 tg(N / 32, K / 32);
        transpose_cvt<<<tg, 256, 0, stream>>>(wte, wt, K, N);

        const int nblocks = (M / 256) * (N / 256);   // 512
        gemm_bf16_flat<<<nblocks, 512, 0, stream>>>(xb, wt, out);
    } else {
        dim3 g(N / 16, M / 16);
        gemm_f32_fallback<<<g, 256, 0, stream>>>(x, wte, out, M, N, K);
    }
}